// Round 1
// baseline (784.456 us; speedup 1.0000x reference)
//
#include <hip/hip_runtime.h>

#define S_LEN 2048
#define D_MODEL 1024
#define NH 16
#define DH 64

// ---------------------------------------------------------------------------
// fp32 tiled GEMM: C[M,N] = A[M,K] @ B[K,N].  64x64 tile, 256 thr, 4x4 micro.
// ---------------------------------------------------------------------------
__global__ __launch_bounds__(256) void gemm_f32(
    const float* __restrict__ A, const float* __restrict__ B, float* __restrict__ C,
    int M, int N, int K)
{
  const int t  = threadIdx.x;
  const int tx = t & 15, ty = t >> 4;
  const int n0 = blockIdx.x * 64, m0 = blockIdx.y * 64;
  __shared__ float As[16][68];   // As[k][m] (transposed store, pad 68)
  __shared__ float Bs[16][68];   // Bs[k][n]
  float acc[4][4] = {};
  const int mA = t >> 2, kqA = t & 3;   // A tile loader: row m, k-quarter
  const int kB = t >> 4, nqB = t & 15;  // B tile loader: row k, n-quarter

  for (int k0 = 0; k0 < K; k0 += 16) {
    float4 a4 = *(const float4*)(A + (size_t)(m0 + mA) * K + k0 + kqA * 4);
    float4 b4 = *(const float4*)(B + (size_t)(k0 + kB) * N + n0 + nqB * 4);
    As[kqA*4+0][mA] = a4.x;
    As[kqA*4+1][mA] = a4.y;
    As[kqA*4+2][mA] = a4.z;
    As[kqA*4+3][mA] = a4.w;
    *(float4*)&Bs[kB][nqB*4] = b4;
    __syncthreads();
#pragma unroll
    for (int kk = 0; kk < 16; kk++) {
      float4 av = *(const float4*)&As[kk][ty*4];
      float4 bv = *(const float4*)&Bs[kk][tx*4];
      float a[4] = {av.x, av.y, av.z, av.w};
      float b[4] = {bv.x, bv.y, bv.z, bv.w};
#pragma unroll
      for (int i = 0; i < 4; i++)
#pragma unroll
        for (int j = 0; j < 4; j++)
          acc[i][j] = fmaf(a[i], b[j], acc[i][j]);
    }
    __syncthreads();
  }
#pragma unroll
  for (int i = 0; i < 4; i++) {
    float4 cv = make_float4(acc[i][0], acc[i][1], acc[i][2], acc[i][3]);
    *(float4*)(C + (size_t)(m0 + ty*4 + i) * N + n0 + tx*4) = cv;
  }
}

// ---------------------------------------------------------------------------
// Flash-style causal attention + Infini-memory retrieval + gate, per
// (head, 64-row q-tile) block.  Writes blended o[s][h*64+c].
// ---------------------------------------------------------------------------
__global__ __launch_bounds__(256) void attn_flash(
    const float* __restrict__ q, const float* __restrict__ kmat,
    const float* __restrict__ vmat, const float* __restrict__ Mmem,
    const float* __restrict__ zmem, const float* __restrict__ beta,
    float* __restrict__ o)
{
  const int h  = blockIdx.y;
  const int qt = blockIdx.x;
  const int s0 = qt * 64;
  const int t  = threadIdx.x;
  const int tx = t & 15, ty = t >> 4;   // 4x4 micro-tile owner
  const int rr = t >> 2, part = t & 3;  // per-row softmax worker

  __shared__ float Qt[64*68];   // Qt[c*68 + r] = q[s0+r][h*64+c]
  __shared__ float Kt[64*68];   // Kt[c*68 + j] ; reused as SQ in epilogue
  __shared__ float P [64*68];   // P[r*68 + j] scores/probs ; reused for output
  __shared__ float red4[256];
  __shared__ float mrow[64], lrow[64], arow[64], drow[64];

  // stage Q transposed
#pragma unroll
  for (int i = 0; i < 16; i++) {
    int flat = t + i*256;
    int r = flat >> 6, c = flat & 63;
    Qt[c*68 + r] = q[(size_t)(s0 + r) * D_MODEL + h*DH + c];
  }
  if (t < 64) { mrow[t] = -1e30f; lrow[t] = 0.f; }
  float acc[4][4] = {};
  __syncthreads();

  for (int jt = 0; jt <= qt; jt++) {
    const int j0 = jt * 64;
    // stage K transposed
#pragma unroll
    for (int i = 0; i < 16; i++) {
      int flat = t + i*256;
      int j = flat >> 6, c = flat & 63;
      Kt[c*68 + j] = kmat[(size_t)(j0 + j) * D_MODEL + h*DH + c];
    }
    __syncthreads();

    // scores: sc[i][j] = sum_c Q[r][c] * K[j][c]
    float sc[4][4] = {};
#pragma unroll 8
    for (int c = 0; c < 64; c++) {
      float4 av = *(const float4*)&Qt[c*68 + ty*4];
      float4 bv = *(const float4*)&Kt[c*68 + tx*4];
      float a[4] = {av.x, av.y, av.z, av.w};
      float b[4] = {bv.x, bv.y, bv.z, bv.w};
#pragma unroll
      for (int i = 0; i < 4; i++)
#pragma unroll
        for (int j = 0; j < 4; j++)
          sc[i][j] = fmaf(a[i], b[j], sc[i][j]);
    }
#pragma unroll
    for (int i = 0; i < 4; i++)
#pragma unroll
      for (int j = 0; j < 4; j++) {
        int r = ty*4 + i, jj = tx*4 + j;
        float sv = sc[i][j] * 0.125f;           // 1/sqrt(64)
        if (jt == qt && jj > r) sv = -1e30f;    // causal mask
        P[r*68 + jj] = sv;
      }
    __syncthreads();

    // tile row max
    float lmax = -1e30f;
#pragma unroll
    for (int jj = 0; jj < 16; jj++)
      lmax = fmaxf(lmax, P[rr*68 + part + jj*4]);
    red4[rr*4 + part] = lmax;
    __syncthreads();
    if (t < 64) {
      float tm = fmaxf(fmaxf(red4[t*4], red4[t*4+1]), fmaxf(red4[t*4+2], red4[t*4+3]));
      float mn = fmaxf(mrow[t], tm);
      arow[t] = __expf(mrow[t] - mn);
      mrow[t] = mn;
    }
    __syncthreads();

    // exp + row sum
    float lsum = 0.f;
    float mr = mrow[rr];
#pragma unroll
    for (int jj = 0; jj < 16; jj++) {
      int idx = rr*68 + part + jj*4;
      float e = __expf(P[idx] - mr);
      P[idx] = e;
      lsum += e;
    }
    red4[rr*4 + part] = lsum;
    __syncthreads();
    if (t < 64)
      lrow[t] = lrow[t]*arow[t] + red4[t*4] + red4[t*4+1] + red4[t*4+2] + red4[t*4+3];
    __syncthreads();

    // O = O*alpha + P @ V   (V straight from global, L1-resident)
    {
      float al[4];
#pragma unroll
      for (int i = 0; i < 4; i++) al[i] = arow[ty*4 + i];
#pragma unroll
      for (int i = 0; i < 4; i++)
#pragma unroll
        for (int j = 0; j < 4; j++) acc[i][j] *= al[i];
#pragma unroll 4
      for (int j = 0; j < 64; j++) {
        float4 vv = *(const float4*)(vmat + (size_t)(j0 + j) * D_MODEL + h*DH + tx*4);
        float p0 = P[(ty*4+0)*68 + j];
        float p1 = P[(ty*4+1)*68 + j];
        float p2 = P[(ty*4+2)*68 + j];
        float p3 = P[(ty*4+3)*68 + j];
        acc[0][0] = fmaf(p0, vv.x, acc[0][0]); acc[0][1] = fmaf(p0, vv.y, acc[0][1]);
        acc[0][2] = fmaf(p0, vv.z, acc[0][2]); acc[0][3] = fmaf(p0, vv.w, acc[0][3]);
        acc[1][0] = fmaf(p1, vv.x, acc[1][0]); acc[1][1] = fmaf(p1, vv.y, acc[1][1]);
        acc[1][2] = fmaf(p1, vv.z, acc[1][2]); acc[1][3] = fmaf(p1, vv.w, acc[1][3]);
        acc[2][0] = fmaf(p2, vv.x, acc[2][0]); acc[2][1] = fmaf(p2, vv.y, acc[2][1]);
        acc[2][2] = fmaf(p2, vv.z, acc[2][2]); acc[2][3] = fmaf(p2, vv.w, acc[2][3]);
        acc[3][0] = fmaf(p3, vv.x, acc[3][0]); acc[3][1] = fmaf(p3, vv.y, acc[3][1]);
        acc[3][2] = fmaf(p3, vv.z, acc[3][2]); acc[3][3] = fmaf(p3, vv.w, acc[3][3]);
      }
    }
    __syncthreads();
  }

  // ---- epilogue: A_mem (linear memory read) + gate blend ----
  // SQ = sigma(Q) into Kt
#pragma unroll
  for (int i = 0; i < 16; i++) {
    int flat = t + i*256;
    int r = flat & 63, c = flat >> 6;
    float qv = Qt[c*68 + r];
    Kt[c*68 + r] = qv > 0.f ? qv + 1.f : __expf(qv);   // elu(x)+1
  }
  __syncthreads();
  // den[r] = sum_c SQ[c][r] * z[h][c]
  {
    float ds = 0.f;
#pragma unroll
    for (int cc = 0; cc < 16; cc++) {
      int c = part + cc*4;
      ds = fmaf(Kt[c*68 + rr], zmem[h*DH + c], ds);
    }
    red4[rr*4 + part] = ds;
  }
  __syncthreads();
  if (t < 64)
    drow[t] = red4[t*4] + red4[t*4+1] + red4[t*4+2] + red4[t*4+3] + 1e-6f;
  __syncthreads();

  // num[r][c] = sum_dd SQ[dd][r] * M[h][dd][c]
  float nacc[4][4] = {};
#pragma unroll 8
  for (int dd = 0; dd < 64; dd++) {
    float4 av = *(const float4*)&Kt[dd*68 + ty*4];
    float4 bv = *(const float4*)(Mmem + (size_t)h*4096 + dd*64 + tx*4);
    float a[4] = {av.x, av.y, av.z, av.w};
    float b[4] = {bv.x, bv.y, bv.z, bv.w};
#pragma unroll
    for (int i = 0; i < 4; i++)
#pragma unroll
      for (int j = 0; j < 4; j++)
        nacc[i][j] = fmaf(a[i], b[j], nacc[i][j]);
  }
  float g = 1.f / (1.f + __expf(-beta[h]));
#pragma unroll
  for (int i = 0; i < 4; i++)
#pragma unroll
    for (int j = 0; j < 4; j++) {
      int r = ty*4 + i, c = tx*4 + j;
      float adot = acc[i][j] / lrow[r];
      float amem = nacc[i][j] / drow[r];
      P[r*68 + c] = g*amem + (1.f - g)*adot;
    }
  __syncthreads();
#pragma unroll
  for (int i = 0; i < 16; i++) {
    int flat = t + i*256;
    int r = flat >> 6, c = flat & 63;
    o[(size_t)(s0 + r) * D_MODEL + h*DH + c] = P[r*68 + c];
  }
}

// ---------------------------------------------------------------------------
// init: copy M, z into output regions (harness poisons d_out before launch)
// ---------------------------------------------------------------------------
__global__ __launch_bounds__(256) void init_out(
    const float* __restrict__ M, const float* __restrict__ z,
    float* __restrict__ Mo, float* __restrict__ zo)
{
  int i = blockIdx.x * 256 + threadIdx.x;
  if (i < NH*DH*DH) Mo[i] = M[i];
  if (i < NH*DH)    zo[i] = z[i];
}

// ---------------------------------------------------------------------------
// memory update: M_new[h][d][e] += sum_s sigma(k[s][h,d]) * v[s][h,e]
//                z_new[h][d]    += sum_s sigma(k[s][h,d])
// grid (16 s-chunks, 16 heads); atomicAdd into pre-initialized output.
// ---------------------------------------------------------------------------
__global__ __launch_bounds__(256) void update_mem(
    const float* __restrict__ kmat, const float* __restrict__ vmat,
    float* __restrict__ Mout, float* __restrict__ zout)
{
  const int h  = blockIdx.y, scnk = blockIdx.x;
  const int t  = threadIdx.x;
  const int dd = t >> 2, eq = t & 3;   // thread owns (dd, e in [eq*16, eq*16+16))
  float accM[16] = {};
  float accZ = 0.f;
  for (int s = scnk*128; s < scnk*128 + 128; s++) {
    float kv = kmat[(size_t)s * D_MODEL + h*DH + dd];
    float sk = kv > 0.f ? kv + 1.f : __expf(kv);
    const float4* vrow = (const float4*)(vmat + (size_t)s * D_MODEL + h*DH + eq*16);
#pragma unroll
    for (int i4 = 0; i4 < 4; i4++) {
      float4 vv = vrow[i4];
      accM[i4*4+0] = fmaf(sk, vv.x, accM[i4*4+0]);
      accM[i4*4+1] = fmaf(sk, vv.y, accM[i4*4+1]);
      accM[i4*4+2] = fmaf(sk, vv.z, accM[i4*4+2]);
      accM[i4*4+3] = fmaf(sk, vv.w, accM[i4*4+3]);
    }
    accZ += sk;
  }
  float* Mo = Mout + (size_t)h*4096 + dd*64 + eq*16;
#pragma unroll
  for (int i = 0; i < 16; i++) atomicAdd(Mo + i, accM[i]);
  if (eq == 0) atomicAdd(zout + h*DH + dd, accZ);
}

// ---------------------------------------------------------------------------
extern "C" void kernel_launch(void* const* d_in, const int* in_sizes, int n_in,
                              void* d_out, int out_size, void* d_ws, size_t ws_size,
                              hipStream_t stream) {
  const float* x    = (const float*)d_in[0];
  const float* M    = (const float*)d_in[1];
  const float* z    = (const float*)d_in[2];
  const float* Wq   = (const float*)d_in[3];
  const float* Wk   = (const float*)d_in[4];
  const float* Wv   = (const float*)d_in[5];
  const float* Wo   = (const float*)d_in[6];
  const float* beta = (const float*)d_in[7];

  float* out  = (float*)d_out;                 // [2048,1024]
  float* Mout = out + (size_t)S_LEN * D_MODEL; // [16,64,64]
  float* zout = Mout + NH*DH*DH;               // [16,64]

  float* q = (float*)d_ws;
  float* k = q + (size_t)S_LEN * D_MODEL;
  float* v = k + (size_t)S_LEN * D_MODEL;
  float* o = v + (size_t)S_LEN * D_MODEL;

  dim3 gg(D_MODEL/64, S_LEN/64);  // (16, 32)
  gemm_f32<<<gg, 256, 0, stream>>>(x, Wq, q, S_LEN, D_MODEL, D_MODEL);
  gemm_f32<<<gg, 256, 0, stream>>>(x, Wk, k, S_LEN, D_MODEL, D_MODEL);
  gemm_f32<<<gg, 256, 0, stream>>>(x, Wv, v, S_LEN, D_MODEL, D_MODEL);

  attn_flash<<<dim3(S_LEN/64, NH), 256, 0, stream>>>(q, k, v, M, z, beta, o);

  gemm_f32<<<gg, 256, 0, stream>>>(o, Wo, out, S_LEN, D_MODEL, D_MODEL);

  init_out<<<dim3(NH*DH*DH/256), 256, 0, stream>>>(M, z, Mout, zout);
  update_mem<<<dim3(16, NH), 256, 0, stream>>>(k, v, Mout, zout);
}